// Round 1
// baseline (4411.161 us; speedup 1.0000x reference)
//
#include <hip/hip_runtime.h>
#include <hip/hip_bf16.h>

// Problem constants (from reference setup_inputs)
#define NB 32    // batch
#define CC 64    // channels
#define VV 500   // nodes
#define LL 64    // time length
#define EE 10    // embedding dim
#define CO 64    // out channels
#define DIL 2    // dilation / shift step

typedef unsigned short u16;
typedef unsigned int   u32;

__device__ __forceinline__ float bf2f(u16 u) {
    union { u32 i; float f; } c; c.i = ((u32)u) << 16; return c.f;
}
__device__ __forceinline__ u16 f2bf(float f) {
    union { float f; u32 i; } c; c.f = f;
    u32 x = c.i;
    u32 r = (x + 0x7fffu + ((x >> 16) & 1u)) >> 16; // RNE
    return (u16)r;
}

// ---------------------------------------------------------------------------
// K0: embedding affine update
//   nv1t[v][e] = sum_f nv1[v][f]*et_w[f][e] + et_b[e]      ([V][E] row-major)
//   nv2t[e][v] = sum_f nv2[f][v]*et_w[f][e] + et_b[e]      ([E][V] row-major)
// ---------------------------------------------------------------------------
__global__ void emb_kernel(const float* __restrict__ nv1, const float* __restrict__ nv2,
                           const float* __restrict__ et_w, const float* __restrict__ et_b,
                           float* __restrict__ nv1t, float* __restrict__ nv2t) {
    int idx = blockIdx.x * blockDim.x + threadIdx.x;
    if (idx < VV * EE) {
        int v = idx / EE, e = idx - v * EE;
        float s = et_b[e];
        #pragma unroll
        for (int f = 0; f < EE; f++) s += nv1[v * EE + f] * et_w[f * EE + e];
        nv1t[idx] = s;
    } else if (idx < 2 * VV * EE) {
        int k = idx - VV * EE;
        int e = k / VV, v = k - e * VV;
        float s = et_b[e];
        #pragma unroll
        for (int f = 0; f < EE; f++) s += nv2[f * VV + v] * et_w[f * EE + e];
        nv2t[k] = s;
    }
}

// ---------------------------------------------------------------------------
// K1: adjacency  At[w][v] = softmax_w(relu(p1[v,:] . p2[:,w]))   (stored transposed)
// One wave (64 threads) per row v.
// ---------------------------------------------------------------------------
__global__ __launch_bounds__(64) void adj_kernel(const float* __restrict__ p1,
                                                 const float* __restrict__ p2,
                                                 float* __restrict__ At) {
    const int v = blockIdx.x;
    const int lane = threadIdx.x;
    float e1[EE];
    #pragma unroll
    for (int e = 0; e < EE; e++) e1[e] = p1[v * EE + e];

    float r[8];
    float m = -1e30f;
    #pragma unroll
    for (int j = 0; j < 8; j++) {
        int w = lane + 64 * j;
        if (w < VV) {
            float s = 0.f;
            #pragma unroll
            for (int e = 0; e < EE; e++) s += e1[e] * p2[e * VV + w];
            r[j] = fmaxf(s, 0.f);
            m = fmaxf(m, r[j]);
        } else {
            r[j] = -1e30f;
        }
    }
    #pragma unroll
    for (int off = 32; off > 0; off >>= 1) m = fmaxf(m, __shfl_xor(m, off));

    float p[8];
    float sum = 0.f;
    #pragma unroll
    for (int j = 0; j < 8; j++) {
        int w = lane + 64 * j;
        if (w < VV) { p[j] = expf(r[j] - m); sum += p[j]; }
    }
    #pragma unroll
    for (int off = 32; off > 0; off >>= 1) sum += __shfl_xor(sum, off);
    float inv = 1.f / sum;
    #pragma unroll
    for (int j = 0; j < 8; j++) {
        int w = lane + 64 * j;
        if (w < VV) At[(size_t)w * VV + v] = p[j] * inv;
    }
}

// ---------------------------------------------------------------------------
// K2: hop  xout[nc][w][l] = sum_v At[w][v] * xr[nc][v][l],
//     xr[v][l] = X[v][l-shift] (0 if l<shift).
// Block = one (n,c). X plane staged in LDS as bf16 (64 KB). Each thread owns
// a 4l x 8w fp32 accumulator tile; 4 w-chunks of 128.
// ---------------------------------------------------------------------------
template<int IN_BF16>
__global__ __launch_bounds__(256) void hop_kernel(const void* __restrict__ xin_,
                                                  const float* __restrict__ At,
                                                  u16* __restrict__ xout,
                                                  int shift) {
    extern __shared__ u16 lds[];   // [VV][LL] bf16, already shifted
    const int nc = blockIdx.x;
    const size_t base = (size_t)nc * (VV * LL);

    if (IN_BF16) {
        const u16* xi = (const u16*)xin_ + base;
        if (shift == 0) {
            const ushort4* src = (const ushort4*)xi;
            for (int idx = threadIdx.x; idx < VV * LL / 4; idx += 256)
                ((ushort4*)lds)[idx] = src[idx];
        } else {
            for (int idx = threadIdx.x; idx < VV * LL; idx += 256) {
                int l = idx & (LL - 1);
                lds[idx] = (l >= shift) ? xi[idx - shift] : (u16)0;
            }
        }
    } else {
        const float* xi = (const float*)xin_ + base;
        if (shift == 0) {
            for (int idx = threadIdx.x; idx < VV * LL / 4; idx += 256) {
                float4 f = ((const float4*)xi)[idx];
                ushort4 o;
                o.x = f2bf(f.x); o.y = f2bf(f.y); o.z = f2bf(f.z); o.w = f2bf(f.w);
                ((ushort4*)lds)[idx] = o;
            }
        } else {
            for (int idx = threadIdx.x; idx < VV * LL; idx += 256) {
                int l = idx & (LL - 1);
                lds[idx] = (l >= shift) ? f2bf(xi[idx - shift]) : (u16)0;
            }
        }
    }
    __syncthreads();

    const int lq = threadIdx.x & 15;
    const int wg = threadIdx.x >> 4;
    const int lb = lq * 4;
    u16* xo = xout + base;

    for (int w0 = 0; w0 < VV; w0 += 128) {
        const int wbase = w0 + wg * 8;
        float acc[8][4];
        #pragma unroll
        for (int j = 0; j < 8; j++) { acc[j][0] = 0.f; acc[j][1] = 0.f; acc[j][2] = 0.f; acc[j][3] = 0.f; }
        const float* ap[8];
        #pragma unroll
        for (int j = 0; j < 8; j++) {
            int w = wbase + j; if (w >= VV) w = VV - 1;
            ap[j] = At + (size_t)w * VV;
        }
        #pragma unroll 2
        for (int v = 0; v < VV; v++) {
            ushort4 xu = *(const ushort4*)&lds[v * LL + lb];
            float x0 = bf2f(xu.x), x1v = bf2f(xu.y), x2v = bf2f(xu.z), x3v = bf2f(xu.w);
            #pragma unroll
            for (int j = 0; j < 8; j++) {
                float a = ap[j][v];
                acc[j][0] += a * x0; acc[j][1] += a * x1v;
                acc[j][2] += a * x2v; acc[j][3] += a * x3v;
            }
        }
        #pragma unroll
        for (int j = 0; j < 8; j++) {
            int w = wbase + j;
            if (w < VV) {
                u16* p = xo + w * LL + lb;
                p[0] = f2bf(acc[j][0]); p[1] = f2bf(acc[j][1]);
                p[2] = f2bf(acc[j][2]); p[3] = f2bf(acc[j][3]);
            }
        }
    }
}

// ---------------------------------------------------------------------------
// K3: MLP  out[n,o,v,l] = b[o] + sum_{c<192} W[o,c]*H[c], H = concat(x,x1,x2)
// Block = one (n,v). H[192][64] and W[64][192] staged in LDS as bf16.
// Thread: l = tid&63, og = tid>>6, owns o = og*16 + j (j<16).
// ---------------------------------------------------------------------------
__global__ __launch_bounds__(256) void mlp_kernel(const float* __restrict__ x,
                                                  const u16* __restrict__ x1,
                                                  const u16* __restrict__ x2,
                                                  const float* __restrict__ w,
                                                  const float* __restrict__ b,
                                                  float* __restrict__ out) {
    __shared__ u16 hs[3 * CC * LL];     // 192*64 bf16 = 24576 B
    __shared__ u16 wsm[CO * 3 * CC];    // 64*192 bf16 = 24576 B
    __shared__ float bs[CO];
    const int nv = blockIdx.x;
    const int n = nv / VV;
    const int v = nv - n * VV;

    for (int idx = threadIdx.x; idx < CO * 3 * CC; idx += 256) wsm[idx] = f2bf(w[idx]);
    if (threadIdx.x < CO) bs[threadIdx.x] = b[threadIdx.x];

    const size_t bnv = (size_t)n * CC * VV * LL + (size_t)v * LL;
    for (int idx = threadIdx.x; idx < CC * LL; idx += 256) {
        int c = idx >> 6, l = idx & 63;
        size_t g = bnv + (size_t)c * (VV * LL) + l;
        hs[idx] = f2bf(x[g]);
        hs[CC * LL + idx] = x1[g];
        hs[2 * CC * LL + idx] = x2[g];
    }
    __syncthreads();

    const int l = threadIdx.x & 63;
    const int og = threadIdx.x >> 6;
    float acc[16];
    #pragma unroll
    for (int j = 0; j < 16; j++) acc[j] = 0.f;

    #pragma unroll 4
    for (int c = 0; c < 3 * CC; c++) {
        float h = bf2f(hs[c * LL + l]);
        #pragma unroll
        for (int j = 0; j < 16; j++)
            acc[j] += h * bf2f(wsm[(og * 16 + j) * (3 * CC) + c]);
    }

    const size_t obase = (size_t)n * CO * VV * LL + (size_t)v * LL + l;
    #pragma unroll
    for (int j = 0; j < 16; j++) {
        int o = og * 16 + j;
        out[obase + (size_t)o * (VV * LL)] = acc[j] + bs[o];
    }
}

// ---------------------------------------------------------------------------
extern "C" void kernel_launch(void* const* d_in, const int* in_sizes, int n_in,
                              void* d_out, int out_size, void* d_ws, size_t ws_size,
                              hipStream_t stream) {
    const float* x     = (const float*)d_in[0];
    const float* nv1   = (const float*)d_in[1];
    const float* nv2   = (const float*)d_in[2];
    const float* et_w  = (const float*)d_in[3];
    const float* et_b  = (const float*)d_in[4];
    const float* mlp_w = (const float*)d_in[5];
    const float* mlp_b = (const float*)d_in[6];
    float* out = (float*)d_out;

    // Workspace layout (~264.2 MB total):
    //   At0, At1: transposed adjacencies, fp32 [V][V]   (1 MB each)
    //   nv1t, nv2t: updated embeddings                  (20 KB each)
    //   x1, x2: hop outputs, bf16 [N][C][V][L]          (131 MB each)
    char* wsb = (char*)d_ws;
    size_t off = 0;
    auto alloc = [&](size_t bytes) {
        size_t o = off;
        off += (bytes + 255) & ~(size_t)255;
        return o;
    };
    float* At0  = (float*)(wsb + alloc((size_t)VV * VV * 4));
    float* At1  = (float*)(wsb + alloc((size_t)VV * VV * 4));
    float* nv1t = (float*)(wsb + alloc((size_t)VV * EE * 4));
    float* nv2t = (float*)(wsb + alloc((size_t)EE * VV * 4));
    u16*   x1   = (u16*)(wsb + alloc((size_t)NB * CC * VV * LL * 2));
    u16*   x2   = (u16*)(wsb + alloc((size_t)NB * CC * VV * LL * 2));
    (void)in_sizes; (void)n_in; (void)out_size; (void)ws_size;

    emb_kernel<<<(2 * VV * EE + 255) / 256, 256, 0, stream>>>(nv1, nv2, et_w, et_b, nv1t, nv2t);
    adj_kernel<<<VV, 64, 0, stream>>>(nv1, nv2, At0);
    adj_kernel<<<VV, 64, 0, stream>>>(nv1t, nv2t, At1);
    hop_kernel<0><<<NB * CC, 256, VV * LL * 2, stream>>>((const void*)x, At0, x1, 0);
    hop_kernel<1><<<NB * CC, 256, VV * LL * 2, stream>>>((const void*)x1, At1, x2, DIL);
    mlp_kernel<<<NB * VV, 256, 0, stream>>>(x, x1, x2, mlp_w, mlp_b, out);
}

// Round 2
// 1054.303 us; speedup vs baseline: 4.1840x; 4.1840x over previous
//
#include <hip/hip_runtime.h>
#include <hip/hip_bf16.h>

#define NB 32    // batch
#define CC 64    // channels
#define VV 500   // nodes
#define LL 64    // time length
#define EE 10    // embedding dim
#define CO 64    // out channels
#define DIL 2    // dilation / shift step
#define VP 512   // padded V for MFMA (k and m padded)

typedef unsigned short u16;
typedef unsigned int   u32;
typedef __attribute__((ext_vector_type(8))) short bf16x8;
typedef __attribute__((ext_vector_type(4))) float f32x4;

__device__ __forceinline__ float bf2f(u16 u) {
    union { u32 i; float f; } c; c.i = ((u32)u) << 16; return c.f;
}
__device__ __forceinline__ u16 f2bf(float f) {
    union { float f; u32 i; } c; c.f = f;
    u32 x = c.i;
    u32 r = (x + 0x7fffu + ((x >> 16) & 1u)) >> 16; // RNE
    return (u16)r;
}

// ---------------------------------------------------------------------------
// K0: embedding affine update (unchanged)
// ---------------------------------------------------------------------------
__global__ void emb_kernel(const float* __restrict__ nv1, const float* __restrict__ nv2,
                           const float* __restrict__ et_w, const float* __restrict__ et_b,
                           float* __restrict__ nv1t, float* __restrict__ nv2t) {
    int idx = blockIdx.x * blockDim.x + threadIdx.x;
    if (idx < VV * EE) {
        int v = idx / EE, e = idx - v * EE;
        float s = et_b[e];
        #pragma unroll
        for (int f = 0; f < EE; f++) s += nv1[v * EE + f] * et_w[f * EE + e];
        nv1t[idx] = s;
    } else if (idx < 2 * VV * EE) {
        int k = idx - VV * EE;
        int e = k / VV, v = k - e * VV;
        float s = et_b[e];
        #pragma unroll
        for (int f = 0; f < EE; f++) s += nv2[f * VV + v] * et_w[f * EE + e];
        nv2t[k] = s;
    }
}

// ---------------------------------------------------------------------------
// K1: adjacency, bf16, zero-padded to [VP][VP], stored transposed:
//   Atb[w][v] = softmax_w(relu(p1[v,:].p2[:,w]))  (w<VV,v<VV), else 0.
// One wave per column v (512 blocks).
// ---------------------------------------------------------------------------
__global__ __launch_bounds__(64) void adj_kernel(const float* __restrict__ p1,
                                                 const float* __restrict__ p2,
                                                 u16* __restrict__ Atb) {
    const int v = blockIdx.x;     // 0..VP-1
    const int lane = threadIdx.x;
    if (v >= VV) {
        #pragma unroll
        for (int j = 0; j < 8; j++) Atb[(size_t)(lane + 64 * j) * VP + v] = 0;
        return;
    }
    float e1[EE];
    #pragma unroll
    for (int e = 0; e < EE; e++) e1[e] = p1[v * EE + e];

    float r[8];
    float m = -1e30f;
    #pragma unroll
    for (int j = 0; j < 8; j++) {
        int w = lane + 64 * j;
        if (w < VV) {
            float s = 0.f;
            #pragma unroll
            for (int e = 0; e < EE; e++) s += e1[e] * p2[e * VV + w];
            r[j] = fmaxf(s, 0.f);
            m = fmaxf(m, r[j]);
        } else {
            r[j] = -1e30f;
        }
    }
    #pragma unroll
    for (int off = 32; off > 0; off >>= 1) m = fmaxf(m, __shfl_xor(m, off));

    float p[8];
    float sum = 0.f;
    #pragma unroll
    for (int j = 0; j < 8; j++) {
        int w = lane + 64 * j;
        if (w < VV) { p[j] = expf(r[j] - m); sum += p[j]; }
    }
    #pragma unroll
    for (int off = 32; off > 0; off >>= 1) sum += __shfl_xor(sum, off);
    float inv = 1.f / sum;
    #pragma unroll
    for (int j = 0; j < 8; j++) {
        int w = lane + 64 * j;
        Atb[(size_t)w * VP + v] = (w < VV) ? f2bf(p[j] * inv) : (u16)0;
    }
}

// ---------------------------------------------------------------------------
// K2: hop via MFMA.  out[w][l] = sum_v Atb[w][v] * Xs[v][l],
//   Xs[v][l] = xin[v][l-SHIFT] (0 if l<SHIFT), per (n,c) plane.
// Block = one plane, 512 threads (8 waves). X staged transposed in LDS as
// Xt[l][v] bf16 (64 KB), XOR-swizzled (byte ^= (l&7)<<4) for conflict-free
// b128 reads + free transpose-scatter writes.
// Wave ww owns output rows [64*ww, 64*ww+64) x all 64 cols:
// 4 row-tiles x 4 col-tiles of 16x16x32 MFMA, K-loop over 512 in steps of 32.
// ---------------------------------------------------------------------------
template<int SHIFT, int IN_BF16>
__global__ __launch_bounds__(512, 4) void hop_mfma(const void* __restrict__ xin_,
                                                   const u16* __restrict__ Atb,
                                                   u16* __restrict__ xout) {
    __shared__ u16 Xt[LL * VP];   // [l][v] swizzled, 64 KB
    const int nc = blockIdx.x;
    const int tid = threadIdx.x;
    const size_t base = (size_t)nc * (VV * LL);

    // ---- stage Xt (transpose + shift + bf16) ----
    // thread handles v-pair p = (tid&31) + 32*it, l-quad l0 = 4*(tid>>5)
    {
        const int lq = tid >> 5;
        const int l0 = lq * 4;
        char* ldsb = (char*)Xt;
        #pragma unroll
        for (int it = 0; it < 8; ++it) {
            const int p = (tid & 31) + 32 * it;
            const int v0 = 2 * p;
            u32 pk0, pk1, pk2, pk3;
            if (v0 < VV) {
                if (IN_BF16) {
                    const u16* r0 = (const u16*)xin_ + base + v0 * LL;
                    const u16* r1 = r0 + LL;
                    u32 a0, a1, b0, b1;
                    if (SHIFT == 0) {
                        a0 = *(const u32*)(r0 + l0); a1 = *(const u32*)(r0 + l0 + 2);
                        b0 = *(const u32*)(r1 + l0); b1 = *(const u32*)(r1 + l0 + 2);
                    } else {
                        if (l0 == 0) {
                            a0 = 0; b0 = 0;
                            a1 = *(const u32*)(r0); b1 = *(const u32*)(r1);
                        } else {
                            a0 = *(const u32*)(r0 + l0 - 2); a1 = *(const u32*)(r0 + l0);
                            b0 = *(const u32*)(r1 + l0 - 2); b1 = *(const u32*)(r1 + l0);
                        }
                    }
                    pk0 = (a0 & 0xffffu) | (b0 << 16);
                    pk1 = (a0 >> 16) | (b0 & 0xffff0000u);
                    pk2 = (a1 & 0xffffu) | (b1 << 16);
                    pk3 = (a1 >> 16) | (b1 & 0xffff0000u);
                } else {
                    const float* r0 = (const float*)xin_ + base + v0 * LL + l0;
                    const float* r1 = r0 + LL;
                    float4 fa = *(const float4*)r0;
                    float4 fb = *(const float4*)r1;
                    pk0 = (u32)f2bf(fa.x) | ((u32)f2bf(fb.x) << 16);
                    pk1 = (u32)f2bf(fa.y) | ((u32)f2bf(fb.y) << 16);
                    pk2 = (u32)f2bf(fa.z) | ((u32)f2bf(fb.z) << 16);
                    pk3 = (u32)f2bf(fa.w) | ((u32)f2bf(fb.w) << 16);
                }
            } else {
                pk0 = pk1 = pk2 = pk3 = 0;
            }
            const int vb = 4 * p;   // byte offset of v-pair within row
            {
                int l = l0 + 0; *(u32*)(ldsb + l * (VP * 2) + (vb ^ ((l & 7) << 4))) = pk0;
                l = l0 + 1;     *(u32*)(ldsb + l * (VP * 2) + (vb ^ ((l & 7) << 4))) = pk1;
                l = l0 + 2;     *(u32*)(ldsb + l * (VP * 2) + (vb ^ ((l & 7) << 4))) = pk2;
                l = l0 + 3;     *(u32*)(ldsb + l * (VP * 2) + (vb ^ ((l & 7) << 4))) = pk3;
            }
        }
    }
    __syncthreads();

    // ---- MFMA main loop ----
    const int lane = tid & 63;
    const int wv = tid >> 6;       // wave 0..7
    const int wr = wv * 64;        // output row base for this wave
    const int r15 = lane & 15;
    const int kg = lane >> 4;      // 0..3

    f32x4 acc[4][4];
    #pragma unroll
    for (int rt = 0; rt < 4; rt++)
        #pragma unroll
        for (int ct = 0; ct < 4; ct++)
            acc[rt][ct] = (f32x4){0.f, 0.f, 0.f, 0.f};

    const char* ldsb = (const char*)Xt;

    #pragma unroll 2
    for (int kb = 0; kb < VP; kb += 32) {
        bf16x8 a[4], b[4];
        #pragma unroll
        for (int rt = 0; rt < 4; rt++) {
            const u16* ap = Atb + (size_t)(wr + rt * 16 + r15) * VP + kb + kg * 8;
            a[rt] = *(const bf16x8*)ap;
        }
        #pragma unroll
        for (int ct = 0; ct < 4; ct++) {
            const int l = ct * 16 + r15;
            const int kbyte = (kb * 2 + kg * 16) ^ ((l & 7) << 4);
            b[ct] = *(const bf16x8*)(ldsb + l * (VP * 2) + kbyte);
        }
        #pragma unroll
        for (int rt = 0; rt < 4; rt++)
            #pragma unroll
            for (int ct = 0; ct < 4; ct++)
                acc[rt][ct] = __builtin_amdgcn_mfma_f32_16x16x32_bf16(a[rt], b[ct], acc[rt][ct], 0, 0, 0);
    }

    // ---- store: C/D layout col=lane&15, row=(lane>>4)*4+reg ----
    u16* xo = xout + base;
    #pragma unroll
    for (int rt = 0; rt < 4; rt++) {
        #pragma unroll
        for (int ct = 0; ct < 4; ct++) {
            const int col = ct * 16 + r15;
            const int wbase = wr + rt * 16 + kg * 4;
            f32x4 c = acc[rt][ct];
            #pragma unroll
            for (int r = 0; r < 4; r++) {
                int w = wbase + r;
                if (w < VV) xo[w * LL + col] = f2bf(c[r]);
            }
        }
    }
}

// ---------------------------------------------------------------------------
// K3: MLP (unchanged): out[n,o,v,l] = b[o] + sum_c W[o,c]*concat(x,x1,x2)[c]
// ---------------------------------------------------------------------------
__global__ __launch_bounds__(256) void mlp_kernel(const float* __restrict__ x,
                                                  const u16* __restrict__ x1,
                                                  const u16* __restrict__ x2,
                                                  const float* __restrict__ w,
                                                  const float* __restrict__ b,
                                                  float* __restrict__ out) {
    __shared__ u16 hs[3 * CC * LL];
    __shared__ u16 wsm[CO * 3 * CC];
    __shared__ float bs[CO];
    const int nv = blockIdx.x;
    const int n = nv / VV;
    const int v = nv - n * VV;

    for (int idx = threadIdx.x; idx < CO * 3 * CC; idx += 256) wsm[idx] = f2bf(w[idx]);
    if (threadIdx.x < CO) bs[threadIdx.x] = b[threadIdx.x];

    const size_t bnv = (size_t)n * CC * VV * LL + (size_t)v * LL;
    for (int idx = threadIdx.x; idx < CC * LL; idx += 256) {
        int c = idx >> 6, l = idx & 63;
        size_t g = bnv + (size_t)c * (VV * LL) + l;
        hs[idx] = f2bf(x[g]);
        hs[CC * LL + idx] = x1[g];
        hs[2 * CC * LL + idx] = x2[g];
    }
    __syncthreads();

    const int l = threadIdx.x & 63;
    const int og = threadIdx.x >> 6;
    float acc[16];
    #pragma unroll
    for (int j = 0; j < 16; j++) acc[j] = 0.f;

    #pragma unroll 4
    for (int c = 0; c < 3 * CC; c++) {
        float h = bf2f(hs[c * LL + l]);
        #pragma unroll
        for (int j = 0; j < 16; j++)
            acc[j] += h * bf2f(wsm[(og * 16 + j) * (3 * CC) + c]);
    }

    const size_t obase = (size_t)n * CO * VV * LL + (size_t)v * LL + l;
    #pragma unroll
    for (int j = 0; j < 16; j++) {
        int o = og * 16 + j;
        out[obase + (size_t)o * (VV * LL)] = acc[j] + bs[o];
    }
}

// ---------------------------------------------------------------------------
extern "C" void kernel_launch(void* const* d_in, const int* in_sizes, int n_in,
                              void* d_out, int out_size, void* d_ws, size_t ws_size,
                              hipStream_t stream) {
    const float* x     = (const float*)d_in[0];
    const float* nv1   = (const float*)d_in[1];
    const float* nv2   = (const float*)d_in[2];
    const float* et_w  = (const float*)d_in[3];
    const float* et_b  = (const float*)d_in[4];
    const float* mlp_w = (const float*)d_in[5];
    const float* mlp_b = (const float*)d_in[6];
    float* out = (float*)d_out;

    char* wsb = (char*)d_ws;
    size_t off = 0;
    auto alloc = [&](size_t bytes) {
        size_t o = off;
        off += (bytes + 255) & ~(size_t)255;
        return o;
    };
    u16*   Atb0 = (u16*)(wsb + alloc((size_t)VP * VP * 2));
    u16*   Atb1 = (u16*)(wsb + alloc((size_t)VP * VP * 2));
    float* nv1t = (float*)(wsb + alloc((size_t)VV * EE * 4));
    float* nv2t = (float*)(wsb + alloc((size_t)EE * VV * 4));
    u16*   x1   = (u16*)(wsb + alloc((size_t)NB * CC * VV * LL * 2));
    u16*   x2   = (u16*)(wsb + alloc((size_t)NB * CC * VV * LL * 2));
    (void)in_sizes; (void)n_in; (void)out_size; (void)ws_size;

    emb_kernel<<<(2 * VV * EE + 255) / 256, 256, 0, stream>>>(nv1, nv2, et_w, et_b, nv1t, nv2t);
    adj_kernel<<<VP, 64, 0, stream>>>(nv1, nv2, Atb0);
    adj_kernel<<<VP, 64, 0, stream>>>(nv1t, nv2t, Atb1);
    hop_mfma<0, 0><<<NB * CC, 512, 0, stream>>>((const void*)x, Atb0, x1);
    hop_mfma<DIL, 1><<<NB * CC, 512, 0, stream>>>((const void*)x1, Atb1, x2);
    mlp_kernel<<<NB * VV, 256, 0, stream>>>(x, x1, x2, mlp_w, mlp_b, out);
}

// Round 3
// 716.954 us; speedup vs baseline: 6.1526x; 1.4705x over previous
//
#include <hip/hip_runtime.h>
#include <hip/hip_bf16.h>

#define NB 32    // batch
#define CC 64    // channels
#define VV 500   // nodes
#define LL 64    // time length
#define EE 10    // embedding dim
#define CO 64    // out channels
#define DIL 2    // dilation / shift step
#define VP 512   // padded V for MFMA (k and m padded)
#define SL (VV * LL)   // 32000 flattened (v,l)

typedef unsigned short u16;
typedef unsigned int   u32;
typedef __attribute__((ext_vector_type(8))) short bf16x8;
typedef __attribute__((ext_vector_type(4))) float f32x4;

__device__ __forceinline__ float bf2f(u16 u) {
    union { u32 i; float f; } c; c.i = ((u32)u) << 16; return c.f;
}
__device__ __forceinline__ u16 f2bf(float f) {
    union { float f; u32 i; } c; c.f = f;
    u32 x = c.i;
    u32 r = (x + 0x7fffu + ((x >> 16) & 1u)) >> 16; // RNE
    return (u16)r;
}

// ---------------------------------------------------------------------------
// K0: embedding affine update + mlp_w -> bf16 conversion
// ---------------------------------------------------------------------------
__global__ void emb_kernel(const float* __restrict__ nv1, const float* __restrict__ nv2,
                           const float* __restrict__ et_w, const float* __restrict__ et_b,
                           const float* __restrict__ mlp_w,
                           float* __restrict__ nv1t, float* __restrict__ nv2t,
                           u16* __restrict__ wb) {
    int idx = blockIdx.x * blockDim.x + threadIdx.x;
    if (idx < VV * EE) {
        int v = idx / EE, e = idx - v * EE;
        float s = et_b[e];
        #pragma unroll
        for (int f = 0; f < EE; f++) s += nv1[v * EE + f] * et_w[f * EE + e];
        nv1t[idx] = s;
    } else if (idx < 2 * VV * EE) {
        int k = idx - VV * EE;
        int e = k / VV, v = k - e * VV;
        float s = et_b[e];
        #pragma unroll
        for (int f = 0; f < EE; f++) s += nv2[f * VV + v] * et_w[f * EE + e];
        nv2t[k] = s;
    } else if (idx < 2 * VV * EE + CO * 3 * CC) {
        int k = idx - 2 * VV * EE;
        wb[k] = f2bf(mlp_w[k]);
    }
}

// ---------------------------------------------------------------------------
// K1: adjacency, bf16, zero-padded to [VP][VP], stored transposed.
// ---------------------------------------------------------------------------
__global__ __launch_bounds__(64) void adj_kernel(const float* __restrict__ p1,
                                                 const float* __restrict__ p2,
                                                 u16* __restrict__ Atb) {
    const int v = blockIdx.x;     // 0..VP-1
    const int lane = threadIdx.x;
    if (v >= VV) {
        #pragma unroll
        for (int j = 0; j < 8; j++) Atb[(size_t)(lane + 64 * j) * VP + v] = 0;
        return;
    }
    float e1[EE];
    #pragma unroll
    for (int e = 0; e < EE; e++) e1[e] = p1[v * EE + e];

    float r[8];
    float m = -1e30f;
    #pragma unroll
    for (int j = 0; j < 8; j++) {
        int w = lane + 64 * j;
        if (w < VV) {
            float s = 0.f;
            #pragma unroll
            for (int e = 0; e < EE; e++) s += e1[e] * p2[e * VV + w];
            r[j] = fmaxf(s, 0.f);
            m = fmaxf(m, r[j]);
        } else {
            r[j] = -1e30f;
        }
    }
    #pragma unroll
    for (int off = 32; off > 0; off >>= 1) m = fmaxf(m, __shfl_xor(m, off));

    float p[8];
    float sum = 0.f;
    #pragma unroll
    for (int j = 0; j < 8; j++) {
        int w = lane + 64 * j;
        if (w < VV) { p[j] = expf(r[j] - m); sum += p[j]; }
    }
    #pragma unroll
    for (int off = 32; off > 0; off >>= 1) sum += __shfl_xor(sum, off);
    float inv = 1.f / sum;
    #pragma unroll
    for (int j = 0; j < 8; j++) {
        int w = lane + 64 * j;
        Atb[(size_t)w * VP + v] = (w < VV) ? f2bf(p[j] * inv) : (u16)0;
    }
}

// ---------------------------------------------------------------------------
// K2: hop via MFMA (unchanged from R1).
// ---------------------------------------------------------------------------
template<int SHIFT, int IN_BF16>
__global__ __launch_bounds__(512, 4) void hop_mfma(const void* __restrict__ xin_,
                                                   const u16* __restrict__ Atb,
                                                   u16* __restrict__ xout) {
    __shared__ u16 Xt[LL * VP];   // [l][v] swizzled, 64 KB
    const int nc = blockIdx.x;
    const int tid = threadIdx.x;
    const size_t base = (size_t)nc * (VV * LL);

    {
        const int lq = tid >> 5;
        const int l0 = lq * 4;
        char* ldsb = (char*)Xt;
        #pragma unroll
        for (int it = 0; it < 8; ++it) {
            const int p = (tid & 31) + 32 * it;
            const int v0 = 2 * p;
            u32 pk0, pk1, pk2, pk3;
            if (v0 < VV) {
                if (IN_BF16) {
                    const u16* r0 = (const u16*)xin_ + base + v0 * LL;
                    const u16* r1 = r0 + LL;
                    u32 a0, a1, b0, b1;
                    if (SHIFT == 0) {
                        a0 = *(const u32*)(r0 + l0); a1 = *(const u32*)(r0 + l0 + 2);
                        b0 = *(const u32*)(r1 + l0); b1 = *(const u32*)(r1 + l0 + 2);
                    } else {
                        if (l0 == 0) {
                            a0 = 0; b0 = 0;
                            a1 = *(const u32*)(r0); b1 = *(const u32*)(r1);
                        } else {
                            a0 = *(const u32*)(r0 + l0 - 2); a1 = *(const u32*)(r0 + l0);
                            b0 = *(const u32*)(r1 + l0 - 2); b1 = *(const u32*)(r1 + l0);
                        }
                    }
                    pk0 = (a0 & 0xffffu) | (b0 << 16);
                    pk1 = (a0 >> 16) | (b0 & 0xffff0000u);
                    pk2 = (a1 & 0xffffu) | (b1 << 16);
                    pk3 = (a1 >> 16) | (b1 & 0xffff0000u);
                } else {
                    const float* r0 = (const float*)xin_ + base + v0 * LL + l0;
                    const float* r1 = r0 + LL;
                    float4 fa = *(const float4*)r0;
                    float4 fb = *(const float4*)r1;
                    pk0 = (u32)f2bf(fa.x) | ((u32)f2bf(fb.x) << 16);
                    pk1 = (u32)f2bf(fa.y) | ((u32)f2bf(fb.y) << 16);
                    pk2 = (u32)f2bf(fa.z) | ((u32)f2bf(fb.z) << 16);
                    pk3 = (u32)f2bf(fa.w) | ((u32)f2bf(fb.w) << 16);
                }
            } else {
                pk0 = pk1 = pk2 = pk3 = 0;
            }
            const int vb = 4 * p;
            {
                int l = l0 + 0; *(u32*)(ldsb + l * (VP * 2) + (vb ^ ((l & 7) << 4))) = pk0;
                l = l0 + 1;     *(u32*)(ldsb + l * (VP * 2) + (vb ^ ((l & 7) << 4))) = pk1;
                l = l0 + 2;     *(u32*)(ldsb + l * (VP * 2) + (vb ^ ((l & 7) << 4))) = pk2;
                l = l0 + 3;     *(u32*)(ldsb + l * (VP * 2) + (vb ^ ((l & 7) << 4))) = pk3;
            }
        }
    }
    __syncthreads();

    const int lane = tid & 63;
    const int wv = tid >> 6;
    const int wr = wv * 64;
    const int r15 = lane & 15;
    const int kg = lane >> 4;

    f32x4 acc[4][4];
    #pragma unroll
    for (int rt = 0; rt < 4; rt++)
        #pragma unroll
        for (int ct = 0; ct < 4; ct++)
            acc[rt][ct] = (f32x4){0.f, 0.f, 0.f, 0.f};

    const char* ldsb = (const char*)Xt;

    #pragma unroll 2
    for (int kb = 0; kb < VP; kb += 32) {
        bf16x8 a[4], b[4];
        #pragma unroll
        for (int rt = 0; rt < 4; rt++) {
            const u16* ap = Atb + (size_t)(wr + rt * 16 + r15) * VP + kb + kg * 8;
            a[rt] = *(const bf16x8*)ap;
        }
        #pragma unroll
        for (int ct = 0; ct < 4; ct++) {
            const int l = ct * 16 + r15;
            const int kbyte = (kb * 2 + kg * 16) ^ ((l & 7) << 4);
            b[ct] = *(const bf16x8*)(ldsb + l * (VP * 2) + kbyte);
        }
        #pragma unroll
        for (int rt = 0; rt < 4; rt++)
            #pragma unroll
            for (int ct = 0; ct < 4; ct++)
                acc[rt][ct] = __builtin_amdgcn_mfma_f32_16x16x32_bf16(a[rt], b[ct], acc[rt][ct], 0, 0, 0);
    }

    u16* xo = xout + base;
    #pragma unroll
    for (int rt = 0; rt < 4; rt++) {
        #pragma unroll
        for (int ct = 0; ct < 4; ct++) {
            const int col = ct * 16 + r15;
            const int wbase = wr + rt * 16 + kg * 4;
            f32x4 c = acc[rt][ct];
            #pragma unroll
            for (int r = 0; r < 4; r++) {
                int w = wbase + r;
                if (w < VV) xo[w * LL + col] = f2bf(c[r]);
            }
        }
    }
}

// ---------------------------------------------------------------------------
// K3: MLP via MFMA.  out[n,o,s] = b[o] + sum_{c<192} W[o,c]*H[c,s],
//   H = concat(x fp32, x1 bf16, x2 bf16) along c;  s = v*LL + l in [0,32000).
// Block: 256 threads (4 waves), one (n, s-tile of 128).
// LDS: Ht[128 s][192 c] bf16, XOR-swizzled (byte ^= (s&7)<<4), 48 KB.
// Staging: threads 0..191 own row c=tid; shfl-pair pack 2 c's into u32 writes.
// Wave wv: o-base (wv&1)*32, s-base (wv>>1)*64; acc[2 o-tiles][4 s-tiles].
// A-frags direct from global wb (k-contiguous, L2-broadcast), preloaded.
// ---------------------------------------------------------------------------
__global__ __launch_bounds__(256, 3) void mlp_mfma(const float* __restrict__ x,
                                                   const u16* __restrict__ x1,
                                                   const u16* __restrict__ x2,
                                                   const u16* __restrict__ wb,
                                                   const float* __restrict__ b,
                                                   float* __restrict__ out) {
    __shared__ u16 Ht[128 * 192];   // 49152 B
    const int bid = blockIdx.x;
    const int n = bid / (SL / 128);
    const int st = bid - n * (SL / 128);
    const int s0 = st * 128;
    const int tid = threadIdx.x;

    if (tid < 3 * CC) {
        const int c = tid;
        char* ldsb = (char*)Ht;
        const int cb = 4 * (c >> 1);     // byte offset of the c-pair in a row
        const int odd = c & 1;
        const float* fsrc = nullptr;
        const u16* bsrc = nullptr;
        if (c < CC)          fsrc = x  + ((size_t)n * CC + c) * SL + s0;
        else if (c < 2 * CC) bsrc = x1 + ((size_t)n * CC + (c - CC)) * SL + s0;
        else                 bsrc = x2 + ((size_t)n * CC + (c - 2 * CC)) * SL + s0;

        #pragma unroll 4
        for (int i = 0; i < 32; i++) {
            const int sl = 4 * i;
            u16 v[4];
            if (c < CC) {
                float4 f = *(const float4*)(fsrc + sl);
                v[0] = f2bf(f.x); v[1] = f2bf(f.y); v[2] = f2bf(f.z); v[3] = f2bf(f.w);
            } else {
                uint2 u = *(const uint2*)(bsrc + sl);
                v[0] = (u16)u.x; v[1] = (u16)(u.x >> 16);
                v[2] = (u16)u.y; v[3] = (u16)(u.y >> 16);
            }
            u32 pk[4];
            #pragma unroll
            for (int j = 0; j < 4; j++) {
                u32 o = (u32)__shfl_xor((int)(u32)v[j], 1);
                pk[j] = odd ? ((o & 0xffffu) | ((u32)v[j] << 16))
                            : ((u32)v[j] | (o << 16));
            }
            const int j0 = odd ? 2 : 0;
            #pragma unroll
            for (int jj = 0; jj < 2; jj++) {
                const int s = sl + j0 + jj;
                *(u32*)(ldsb + s * 384 + (cb ^ ((s & 7) << 4))) = pk[j0 + jj];
            }
        }
    }

    const int lane = tid & 63;
    const int wv = tid >> 6;
    const int obase = (wv & 1) * 32;
    const int sbase = (wv >> 1) * 64;
    const int r15 = lane & 15;
    const int kg = lane >> 4;

    bf16x8 afrag[2][6];
    #pragma unroll
    for (int rt = 0; rt < 2; rt++)
        #pragma unroll
        for (int ks = 0; ks < 6; ks++)
            afrag[rt][ks] = *(const bf16x8*)(wb + (obase + rt * 16 + r15) * (3 * CC) + ks * 32 + kg * 8);

    __syncthreads();

    f32x4 acc[2][4];
    #pragma unroll
    for (int rt = 0; rt < 2; rt++)
        #pragma unroll
        for (int ct = 0; ct < 4; ct++)
            acc[rt][ct] = (f32x4){0.f, 0.f, 0.f, 0.f};

    const char* ldsb = (const char*)Ht;
    #pragma unroll
    for (int ks = 0; ks < 6; ks++) {
        bf16x8 bfr[4];
        #pragma unroll
        for (int ct = 0; ct < 4; ct++) {
            const int s = sbase + ct * 16 + r15;
            bfr[ct] = *(const bf16x8*)(ldsb + s * 384 + ((ks * 64 + kg * 16) ^ ((s & 7) << 4)));
        }
        #pragma unroll
        for (int rt = 0; rt < 2; rt++)
            #pragma unroll
            for (int ct = 0; ct < 4; ct++)
                acc[rt][ct] = __builtin_amdgcn_mfma_f32_16x16x32_bf16(afrag[rt][ks], bfr[ct], acc[rt][ct], 0, 0, 0);
    }

    // epilogue: C/D layout col=lane&15 (s), row=(lane>>4)*4+reg (o)
    #pragma unroll
    for (int rt = 0; rt < 2; rt++) {
        #pragma unroll
        for (int r = 0; r < 4; r++) {
            const int o = obase + rt * 16 + kg * 4 + r;
            const float bias = b[o];
            float* orow = out + ((size_t)n * CO + o) * SL + s0 + sbase;
            #pragma unroll
            for (int ct = 0; ct < 4; ct++)
                orow[ct * 16 + r15] = acc[rt][ct][r] + bias;
        }
    }
}

// ---------------------------------------------------------------------------
extern "C" void kernel_launch(void* const* d_in, const int* in_sizes, int n_in,
                              void* d_out, int out_size, void* d_ws, size_t ws_size,
                              hipStream_t stream) {
    const float* x     = (const float*)d_in[0];
    const float* nv1   = (const float*)d_in[1];
    const float* nv2   = (const float*)d_in[2];
    const float* et_w  = (const float*)d_in[3];
    const float* et_b  = (const float*)d_in[4];
    const float* mlp_w = (const float*)d_in[5];
    const float* mlp_b = (const float*)d_in[6];
    float* out = (float*)d_out;

    char* wsb = (char*)d_ws;
    size_t off = 0;
    auto alloc = [&](size_t bytes) {
        size_t o = off;
        off += (bytes + 255) & ~(size_t)255;
        return o;
    };
    u16*   Atb0 = (u16*)(wsb + alloc((size_t)VP * VP * 2));
    u16*   Atb1 = (u16*)(wsb + alloc((size_t)VP * VP * 2));
    float* nv1t = (float*)(wsb + alloc((size_t)VV * EE * 4));
    float* nv2t = (float*)(wsb + alloc((size_t)EE * VV * 4));
    u16*   wb   = (u16*)(wsb + alloc((size_t)CO * 3 * CC * 2));
    u16*   x1   = (u16*)(wsb + alloc((size_t)NB * CC * VV * LL * 2));
    u16*   x2   = (u16*)(wsb + alloc((size_t)NB * CC * VV * LL * 2));
    (void)in_sizes; (void)n_in; (void)out_size; (void)ws_size;

    const int embN = 2 * VV * EE + CO * 3 * CC;
    emb_kernel<<<(embN + 255) / 256, 256, 0, stream>>>(nv1, nv2, et_w, et_b, mlp_w, nv1t, nv2t, wb);
    adj_kernel<<<VP, 64, 0, stream>>>(nv1, nv2, Atb0);
    adj_kernel<<<VP, 64, 0, stream>>>(nv1t, nv2t, Atb1);
    hop_mfma<0, 0><<<NB * CC, 512, 0, stream>>>((const void*)x, Atb0, x1);
    hop_mfma<DIL, 1><<<NB * CC, 512, 0, stream>>>((const void*)x1, Atb1, x2);
    mlp_mfma<<<NB * (SL / 128), 256, 0, stream>>>(x, x1, x2, wb, mlp_b, out);
}

// Round 4
// 640.953 us; speedup vs baseline: 6.8822x; 1.1186x over previous
//
#include <hip/hip_runtime.h>
#include <hip/hip_bf16.h>

#define NB 32    // batch
#define CC 64    // channels
#define VV 500   // nodes
#define LL 64    // time length
#define EE 10    // embedding dim
#define CO 64    // out channels
#define DIL 2    // dilation / shift step
#define VP 512   // padded V for MFMA (k and m padded)
#define SL (VV * LL)   // 32000 flattened (v,l)

typedef unsigned short u16;
typedef unsigned int   u32;
typedef __attribute__((ext_vector_type(8))) short bf16x8;
typedef __attribute__((ext_vector_type(4))) float f32x4;

__device__ __forceinline__ float bf2f(u16 u) {
    union { u32 i; float f; } c; c.i = ((u32)u) << 16; return c.f;
}
__device__ __forceinline__ u16 f2bf(float f) {
    union { float f; u32 i; } c; c.f = f;
    u32 x = c.i;
    u32 r = (x + 0x7fffu + ((x >> 16) & 1u)) >> 16; // RNE
    return (u16)r;
}

// ---------------------------------------------------------------------------
// K0: embedding affine update + mlp_w -> bf16 conversion
// ---------------------------------------------------------------------------
__global__ void emb_kernel(const float* __restrict__ nv1, const float* __restrict__ nv2,
                           const float* __restrict__ et_w, const float* __restrict__ et_b,
                           const float* __restrict__ mlp_w,
                           float* __restrict__ nv1t, float* __restrict__ nv2t,
                           u16* __restrict__ wb) {
    int idx = blockIdx.x * blockDim.x + threadIdx.x;
    if (idx < VV * EE) {
        int v = idx / EE, e = idx - v * EE;
        float s = et_b[e];
        #pragma unroll
        for (int f = 0; f < EE; f++) s += nv1[v * EE + f] * et_w[f * EE + e];
        nv1t[idx] = s;
    } else if (idx < 2 * VV * EE) {
        int k = idx - VV * EE;
        int e = k / VV, v = k - e * VV;
        float s = et_b[e];
        #pragma unroll
        for (int f = 0; f < EE; f++) s += nv2[f * VV + v] * et_w[f * EE + e];
        nv2t[k] = s;
    } else if (idx < 2 * VV * EE + CO * 3 * CC) {
        int k = idx - 2 * VV * EE;
        wb[k] = f2bf(mlp_w[k]);
    }
}

// ---------------------------------------------------------------------------
// K1: adjacency, bf16, zero-padded to [VP][VP], stored transposed.
// ---------------------------------------------------------------------------
__global__ __launch_bounds__(64) void adj_kernel(const float* __restrict__ p1,
                                                 const float* __restrict__ p2,
                                                 u16* __restrict__ Atb) {
    const int v = blockIdx.x;     // 0..VP-1
    const int lane = threadIdx.x;
    if (v >= VV) {
        #pragma unroll
        for (int j = 0; j < 8; j++) Atb[(size_t)(lane + 64 * j) * VP + v] = 0;
        return;
    }
    float e1[EE];
    #pragma unroll
    for (int e = 0; e < EE; e++) e1[e] = p1[v * EE + e];

    float r[8];
    float m = -1e30f;
    #pragma unroll
    for (int j = 0; j < 8; j++) {
        int w = lane + 64 * j;
        if (w < VV) {
            float s = 0.f;
            #pragma unroll
            for (int e = 0; e < EE; e++) s += e1[e] * p2[e * VV + w];
            r[j] = fmaxf(s, 0.f);
            m = fmaxf(m, r[j]);
        } else {
            r[j] = -1e30f;
        }
    }
    #pragma unroll
    for (int off = 32; off > 0; off >>= 1) m = fmaxf(m, __shfl_xor(m, off));

    float p[8];
    float sum = 0.f;
    #pragma unroll
    for (int j = 0; j < 8; j++) {
        int w = lane + 64 * j;
        if (w < VV) { p[j] = expf(r[j] - m); sum += p[j]; }
    }
    #pragma unroll
    for (int off = 32; off > 0; off >>= 1) sum += __shfl_xor(sum, off);
    float inv = 1.f / sum;
    #pragma unroll
    for (int j = 0; j < 8; j++) {
        int w = lane + 64 * j;
        Atb[(size_t)w * VP + v] = (w < VV) ? f2bf(p[j] * inv) : (u16)0;
    }
}

// ---------------------------------------------------------------------------
// K2: hop via MFMA.  out[w][l] = sum_v Atb[w][v] * Xs[v][l],
//   Xs[v][l] = xin[v][l-SHIFT] (0 if l<SHIFT), per (n,c) plane.
// Staging v2: lane-minor = l (coalesced). Lane (vsub=tid>>4&3, lpos=tid&15)
// loads rows v0, v0+1 scalar at 16 consecutive l -> packs one u32 ->
// swizzled LDS write; per-instr banks = vpair ^ 4*(l&7) = 32 distinct (free).
// ---------------------------------------------------------------------------
template<int SHIFT, int IN_BF16>
__global__ __launch_bounds__(512, 4) void hop_mfma(const void* __restrict__ xin_,
                                                   const u16* __restrict__ Atb,
                                                   u16* __restrict__ xout) {
    __shared__ u16 Xt[LL * VP];   // [l][v] swizzled, 64 KB
    const int nc = blockIdx.x;
    const int tid = threadIdx.x;
    const size_t base = (size_t)nc * (VV * LL);

    {
        char* ldsb = (char*)Xt;
        const int lpos = tid & 15;
        const int vsub = (tid >> 4) & 3;
        const int wv8 = tid >> 6;   // wave 0..7
        const u16* xib = (const u16*)xin_ + base;
        const float* xif = (const float*)xin_ + base;
        #pragma unroll
        for (int g = 0; g < 8; ++g) {
            const int vpg = wv8 * 32 + g * 4 + vsub;   // v-pair index 0..255
            const int v0 = 2 * vpg;
            const bool ok0 = (v0 < VV);
            const bool ok1 = (v0 + 1 < VV);
            #pragma unroll
            for (int lc = 0; lc < 4; ++lc) {
                const int l = lc * 16 + lpos;
                const int sl = l - SHIFT;
                u32 lo = 0, hi = 0;
                if (sl >= 0) {
                    if (IN_BF16) {
                        if (ok0) lo = xib[v0 * LL + sl];
                        if (ok1) hi = xib[(v0 + 1) * LL + sl];
                    } else {
                        if (ok0) lo = f2bf(xif[v0 * LL + sl]);
                        if (ok1) hi = f2bf(xif[(v0 + 1) * LL + sl]);
                    }
                }
                *(u32*)(ldsb + l * (VP * 2) + ((4 * vpg) ^ ((l & 7) << 4))) = lo | (hi << 16);
            }
        }
    }
    __syncthreads();

    const int lane = tid & 63;
    const int wv = tid >> 6;
    const int wr = wv * 64;
    const int r15 = lane & 15;
    const int kg = lane >> 4;

    f32x4 acc[4][4];
    #pragma unroll
    for (int rt = 0; rt < 4; rt++)
        #pragma unroll
        for (int ct = 0; ct < 4; ct++)
            acc[rt][ct] = (f32x4){0.f, 0.f, 0.f, 0.f};

    const char* ldsb = (const char*)Xt;

    #pragma unroll 2
    for (int kb = 0; kb < VP; kb += 32) {
        bf16x8 a[4], b[4];
        #pragma unroll
        for (int rt = 0; rt < 4; rt++) {
            const u16* ap = Atb + (size_t)(wr + rt * 16 + r15) * VP + kb + kg * 8;
            a[rt] = *(const bf16x8*)ap;
        }
        #pragma unroll
        for (int ct = 0; ct < 4; ct++) {
            const int l = ct * 16 + r15;
            const int kbyte = (kb * 2 + kg * 16) ^ ((l & 7) << 4);
            b[ct] = *(const bf16x8*)(ldsb + l * (VP * 2) + kbyte);
        }
        #pragma unroll
        for (int rt = 0; rt < 4; rt++)
            #pragma unroll
            for (int ct = 0; ct < 4; ct++)
                acc[rt][ct] = __builtin_amdgcn_mfma_f32_16x16x32_bf16(a[rt], b[ct], acc[rt][ct], 0, 0, 0);
    }

    u16* xo = xout + base;
    #pragma unroll
    for (int rt = 0; rt < 4; rt++) {
        #pragma unroll
        for (int ct = 0; ct < 4; ct++) {
            const int col = ct * 16 + r15;
            const int wbase = wr + rt * 16 + kg * 4;
            f32x4 c = acc[rt][ct];
            #pragma unroll
            for (int r = 0; r < 4; r++) {
                int w = wbase + r;
                if (w < VV) xo[w * LL + col] = f2bf(c[r]);
            }
        }
    }
}

// ---------------------------------------------------------------------------
// K3: MLP via MFMA.  out[n,o,s] = b[o] + sum_{c<192} W[o,c]*H[c,s],
//   H = concat(x fp32, x1 bf16, x2 bf16) along c;  s = v*LL + l.
// Staging v2: lane (P = cg*16 + tid>>4, spos = tid&15) loads planes 2P, 2P+1
// scalar at 16 consecutive s -> packs u32 -> swizzled write (banks free).
// Wave wv: o-base (wv&1)*32, s-base (wv>>1)*64; acc[2][4]; A-frags global.
// ---------------------------------------------------------------------------
__global__ __launch_bounds__(256, 3) void mlp_mfma(const float* __restrict__ x,
                                                   const u16* __restrict__ x1,
                                                   const u16* __restrict__ x2,
                                                   const u16* __restrict__ wb,
                                                   const float* __restrict__ b,
                                                   float* __restrict__ out) {
    __shared__ u16 Ht[128 * 192];   // 49152 B
    const int bid = blockIdx.x;
    const int n = bid / (SL / 128);
    const int st = bid - n * (SL / 128);
    const int s0 = st * 128;
    const int tid = threadIdx.x;

    const int lane = tid & 63;
    const int wv = tid >> 6;
    const int obase = (wv & 1) * 32;
    const int sbase = (wv >> 1) * 64;
    const int r15 = lane & 15;
    const int kg = lane >> 4;

    // A-fragments from global (L2-broadcast), issued before staging
    bf16x8 afrag[2][6];
    #pragma unroll
    for (int rt = 0; rt < 2; rt++)
        #pragma unroll
        for (int ks = 0; ks < 6; ks++)
            afrag[rt][ks] = *(const bf16x8*)(wb + (obase + rt * 16 + r15) * (3 * CC) + ks * 32 + kg * 8);

    {
        char* ldsb = (char*)Ht;
        const int spos = tid & 15;
        const int psub = tid >> 4;      // 0..15
        #pragma unroll
        for (int cg = 0; cg < 6; ++cg) {
            const int P = cg * 16 + psub;     // c-pair 0..95
            const int c = 2 * P;
            const u16* bsrc = nullptr;
            const float* fsrc = nullptr;
            if (c < CC)          fsrc = x  + ((size_t)n * CC + c) * SL + s0;
            else if (c < 2 * CC) bsrc = x1 + ((size_t)n * CC + (c - CC)) * SL + s0;
            else                 bsrc = x2 + ((size_t)n * CC + (c - 2 * CC)) * SL + s0;
            #pragma unroll
            for (int sc = 0; sc < 8; ++sc) {
                const int sl = sc * 16 + spos;   // 0..127
                u32 lo, hi;
                if (c < CC) {
                    lo = f2bf(fsrc[sl]); hi = f2bf(fsrc[sl + SL]);
                } else {
                    lo = bsrc[sl]; hi = bsrc[sl + SL];
                }
                *(u32*)(ldsb + sl * 384 + ((4 * P) ^ ((sl & 7) << 4))) = lo | (hi << 16);
            }
        }
    }
    __syncthreads();

    f32x4 acc[2][4];
    #pragma unroll
    for (int rt = 0; rt < 2; rt++)
        #pragma unroll
        for (int ct = 0; ct < 4; ct++)
            acc[rt][ct] = (f32x4){0.f, 0.f, 0.f, 0.f};

    const char* ldsb = (const char*)Ht;
    #pragma unroll
    for (int ks = 0; ks < 6; ks++) {
        bf16x8 bfr[4];
        #pragma unroll
        for (int ct = 0; ct < 4; ct++) {
            const int s = sbase + ct * 16 + r15;
            bfr[ct] = *(const bf16x8*)(ldsb + s * 384 + ((ks * 64 + kg * 16) ^ ((s & 7) << 4)));
        }
        #pragma unroll
        for (int rt = 0; rt < 2; rt++)
            #pragma unroll
            for (int ct = 0; ct < 4; ct++)
                acc[rt][ct] = __builtin_amdgcn_mfma_f32_16x16x32_bf16(afrag[rt][ks], bfr[ct], acc[rt][ct], 0, 0, 0);
    }

    // epilogue: C/D layout col=lane&15 (s), row=(lane>>4)*4+reg (o)
    #pragma unroll
    for (int rt = 0; rt < 2; rt++) {
        #pragma unroll
        for (int r = 0; r < 4; r++) {
            const int o = obase + rt * 16 + kg * 4 + r;
            const float bias = b[o];
            float* orow = out + ((size_t)n * CO + o) * SL + s0 + sbase;
            #pragma unroll
            for (int ct = 0; ct < 4; ct++)
                orow[ct * 16 + r15] = acc[rt][ct][r] + bias;
        }
    }
}

// ---------------------------------------------------------------------------
extern "C" void kernel_launch(void* const* d_in, const int* in_sizes, int n_in,
                              void* d_out, int out_size, void* d_ws, size_t ws_size,
                              hipStream_t stream) {
    const float* x     = (const float*)d_in[0];
    const float* nv1   = (const float*)d_in[1];
    const float* nv2   = (const float*)d_in[2];
    const float* et_w  = (const float*)d_in[3];
    const float* et_b  = (const float*)d_in[4];
    const float* mlp_w = (const float*)d_in[5];
    const float* mlp_b = (const float*)d_in[6];
    float* out = (float*)d_out;

    char* wsb = (char*)d_ws;
    size_t off = 0;
    auto alloc = [&](size_t bytes) {
        size_t o = off;
        off += (bytes + 255) & ~(size_t)255;
        return o;
    };
    u16*   Atb0 = (u16*)(wsb + alloc((size_t)VP * VP * 2));
    u16*   Atb1 = (u16*)(wsb + alloc((size_t)VP * VP * 2));
    float* nv1t = (float*)(wsb + alloc((size_t)VV * EE * 4));
    float* nv2t = (float*)(wsb + alloc((size_t)EE * VV * 4));
    u16*   wb   = (u16*)(wsb + alloc((size_t)CO * 3 * CC * 2));
    u16*   x1   = (u16*)(wsb + alloc((size_t)NB * CC * VV * LL * 2));
    u16*   x2   = (u16*)(wsb + alloc((size_t)NB * CC * VV * LL * 2));
    (void)in_sizes; (void)n_in; (void)out_size; (void)ws_size;

    const int embN = 2 * VV * EE + CO * 3 * CC;
    emb_kernel<<<(embN + 255) / 256, 256, 0, stream>>>(nv1, nv2, et_w, et_b, mlp_w, nv1t, nv2t, wb);
    adj_kernel<<<VP, 64, 0, stream>>>(nv1, nv2, Atb0);
    adj_kernel<<<VP, 64, 0, stream>>>(nv1t, nv2t, Atb1);
    hop_mfma<0, 0><<<NB * CC, 512, 0, stream>>>((const void*)x, Atb0, x1);
    hop_mfma<DIL, 1><<<NB * CC, 512, 0, stream>>>((const void*)x1, Atb1, x2);
    mlp_mfma<<<NB * (SL / 128), 256, 0, stream>>>(x, x1, x2, wb, mlp_b, out);
}

// Round 5
// 594.095 us; speedup vs baseline: 7.4250x; 1.0789x over previous
//
#include <hip/hip_runtime.h>
#include <hip/hip_bf16.h>

#define NB 32    // batch
#define CC 64    // channels
#define VV 500   // nodes
#define LL 64    // time length
#define EE 10    // embedding dim
#define CO 64    // out channels
#define DIL 2    // dilation / shift step
#define VP 512   // padded V for MFMA (k and m padded)
#define SL (VV * LL)   // 32000 flattened (v,l)

typedef unsigned short u16;
typedef unsigned int   u32;
typedef __attribute__((ext_vector_type(8))) short bf16x8;
typedef __attribute__((ext_vector_type(4))) float f32x4;

__device__ __forceinline__ float bf2f(u16 u) {
    union { u32 i; float f; } c; c.i = ((u32)u) << 16; return c.f;
}
__device__ __forceinline__ u16 f2bf(float f) {
    union { float f; u32 i; } c; c.f = f;
    u32 x = c.i;
    u32 r = (x + 0x7fffu + ((x >> 16) & 1u)) >> 16; // RNE
    return (u16)r;
}

// ---------------------------------------------------------------------------
// K0: embedding affine update + mlp_w -> bf16 conversion
// ---------------------------------------------------------------------------
__global__ void emb_kernel(const float* __restrict__ nv1, const float* __restrict__ nv2,
                           const float* __restrict__ et_w, const float* __restrict__ et_b,
                           const float* __restrict__ mlp_w,
                           float* __restrict__ nv1t, float* __restrict__ nv2t,
                           u16* __restrict__ wb) {
    int idx = blockIdx.x * blockDim.x + threadIdx.x;
    if (idx < VV * EE) {
        int v = idx / EE, e = idx - v * EE;
        float s = et_b[e];
        #pragma unroll
        for (int f = 0; f < EE; f++) s += nv1[v * EE + f] * et_w[f * EE + e];
        nv1t[idx] = s;
    } else if (idx < 2 * VV * EE) {
        int k = idx - VV * EE;
        int e = k / VV, v = k - e * VV;
        float s = et_b[e];
        #pragma unroll
        for (int f = 0; f < EE; f++) s += nv2[f * VV + v] * et_w[f * EE + e];
        nv2t[k] = s;
    } else if (idx < 2 * VV * EE + CO * 3 * CC) {
        int k = idx - 2 * VV * EE;
        wb[k] = f2bf(mlp_w[k]);
    }
}

// ---------------------------------------------------------------------------
// K1: adjacency, bf16, zero-padded to [VP][VP], stored transposed.
// ---------------------------------------------------------------------------
__global__ __launch_bounds__(64) void adj_kernel(const float* __restrict__ p1,
                                                 const float* __restrict__ p2,
                                                 u16* __restrict__ Atb) {
    const int v = blockIdx.x;     // 0..VP-1
    const int lane = threadIdx.x;
    if (v >= VV) {
        #pragma unroll
        for (int j = 0; j < 8; j++) Atb[(size_t)(lane + 64 * j) * VP + v] = 0;
        return;
    }
    float e1[EE];
    #pragma unroll
    for (int e = 0; e < EE; e++) e1[e] = p1[v * EE + e];

    float r[8];
    float m = -1e30f;
    #pragma unroll
    for (int j = 0; j < 8; j++) {
        int w = lane + 64 * j;
        if (w < VV) {
            float s = 0.f;
            #pragma unroll
            for (int e = 0; e < EE; e++) s += e1[e] * p2[e * VV + w];
            r[j] = fmaxf(s, 0.f);
            m = fmaxf(m, r[j]);
        } else {
            r[j] = -1e30f;
        }
    }
    #pragma unroll
    for (int off = 32; off > 0; off >>= 1) m = fmaxf(m, __shfl_xor(m, off));

    float p[8];
    float sum = 0.f;
    #pragma unroll
    for (int j = 0; j < 8; j++) {
        int w = lane + 64 * j;
        if (w < VV) { p[j] = expf(r[j] - m); sum += p[j]; }
    }
    #pragma unroll
    for (int off = 32; off > 0; off >>= 1) sum += __shfl_xor(sum, off);
    float inv = 1.f / sum;
    #pragma unroll
    for (int j = 0; j < 8; j++) {
        int w = lane + 64 * j;
        Atb[(size_t)w * VP + v] = (w < VV) ? f2bf(p[j] * inv) : (u16)0;
    }
}

// ---------------------------------------------------------------------------
// K2: hop via MFMA.  D[w][l] = sum_v Atb[w][v] * X[v][l]  (UNSHIFTED),
//   epilogue writes out[w][l] = D[w][l-SHIFT] (0 for l<SHIFT).
// Staging v3: wave wv stages rows v in [wv*64, +64). Lane (vsub=lane>>4,
// lquad=lane&15): float4/uint2 loads of rows v0,v0+1 at l-quad 4*lquad
// (16 lanes x 16B = 256B contiguous per row) -> in-lane pair pack ->
// 4 swizzled u32 LDS writes. 16 wide VMEM per thread total.
// ---------------------------------------------------------------------------
template<int SHIFT, int IN_BF16>
__global__ __launch_bounds__(512, 4) void hop_mfma(const void* __restrict__ xin_,
                                                   const u16* __restrict__ Atb,
                                                   u16* __restrict__ xout) {
    __shared__ u16 Xt[LL * VP];   // [l][v] swizzled, 64 KB
    const int nc = blockIdx.x;
    const int tid = threadIdx.x;
    const size_t base = (size_t)nc * (VV * LL);
    const int lane = tid & 63;
    const int wv = tid >> 6;

    // ---- stage (transpose + bf16, no shift) ----
    {
        char* ldsb = (char*)Xt;
        const int lquad = lane & 15;
        const int vsub = lane >> 4;     // 0..3
        const int l0 = 4 * lquad;
        #pragma unroll
        for (int i = 0; i < 8; ++i) {
            const int vp = wv * 32 + i * 4 + vsub;  // v-pair 0..255
            const int v0 = 2 * vp;
            u32 pk0, pk1, pk2, pk3;
            if (v0 < VV) {   // VV even => v0 < VV implies v0+1 < VV
                if (IN_BF16) {
                    const u16* xa = (const u16*)xin_ + base + v0 * LL + l0;
                    uint2 ua = *(const uint2*)xa;
                    uint2 ub = *(const uint2*)(xa + LL);
                    pk0 = (ua.x & 0xffffu) | (ub.x << 16);
                    pk1 = (ua.x >> 16) | (ub.x & 0xffff0000u);
                    pk2 = (ua.y & 0xffffu) | (ub.y << 16);
                    pk3 = (ua.y >> 16) | (ub.y & 0xffff0000u);
                } else {
                    const float* xa = (const float*)xin_ + base + v0 * LL + l0;
                    float4 fa = *(const float4*)xa;
                    float4 fb = *(const float4*)(xa + LL);
                    pk0 = (u32)f2bf(fa.x) | ((u32)f2bf(fb.x) << 16);
                    pk1 = (u32)f2bf(fa.y) | ((u32)f2bf(fb.y) << 16);
                    pk2 = (u32)f2bf(fa.z) | ((u32)f2bf(fb.z) << 16);
                    pk3 = (u32)f2bf(fa.w) | ((u32)f2bf(fb.w) << 16);
                }
            } else {
                pk0 = pk1 = pk2 = pk3 = 0;
            }
            const int vb = 4 * vp;
            int l = l0;
            *(u32*)(ldsb + l * (VP * 2) + (vb ^ ((l & 7) << 4))) = pk0; l++;
            *(u32*)(ldsb + l * (VP * 2) + (vb ^ ((l & 7) << 4))) = pk1; l++;
            *(u32*)(ldsb + l * (VP * 2) + (vb ^ ((l & 7) << 4))) = pk2; l++;
            *(u32*)(ldsb + l * (VP * 2) + (vb ^ ((l & 7) << 4))) = pk3;
        }
    }
    __syncthreads();

    // ---- MFMA main loop ----
    const int wr = wv * 64;
    const int r15 = lane & 15;
    const int kg = lane >> 4;

    f32x4 acc[4][4];
    #pragma unroll
    for (int rt = 0; rt < 4; rt++)
        #pragma unroll
        for (int ct = 0; ct < 4; ct++)
            acc[rt][ct] = (f32x4){0.f, 0.f, 0.f, 0.f};

    const char* ldsb = (const char*)Xt;
    const u16* arow[4];
    #pragma unroll
    for (int rt = 0; rt < 4; rt++)
        arow[rt] = Atb + (size_t)(wr + rt * 16 + r15) * VP + kg * 8;
    int lrow[4], lswz[4];
    #pragma unroll
    for (int ct = 0; ct < 4; ct++) {
        const int l = ct * 16 + r15;
        lrow[ct] = l * (VP * 2);
        lswz[ct] = (l & 7) << 4;
    }

    #pragma unroll
    for (int kb = 0; kb < VP; kb += 32) {
        bf16x8 a[4], b[4];
        #pragma unroll
        for (int rt = 0; rt < 4; rt++)
            a[rt] = *(const bf16x8*)(arow[rt] + kb);
        #pragma unroll
        for (int ct = 0; ct < 4; ct++)
            b[ct] = *(const bf16x8*)(ldsb + lrow[ct] + ((kb * 2 + kg * 16) ^ lswz[ct]));
        #pragma unroll
        for (int rt = 0; rt < 4; rt++)
            #pragma unroll
            for (int ct = 0; ct < 4; ct++)
                acc[rt][ct] = __builtin_amdgcn_mfma_f32_16x16x32_bf16(a[rt], b[ct], acc[rt][ct], 0, 0, 0);
    }

    // ---- store with epilogue shift: out[w][col+SHIFT] = D[w][col], out[w][<SHIFT]=0
    u16* xo = xout + base;
    #pragma unroll
    for (int rt = 0; rt < 4; rt++) {
        #pragma unroll
        for (int ct = 0; ct < 4; ct++) {
            const int col = ct * 16 + r15;
            const int wbase = wr + rt * 16 + kg * 4;
            f32x4 c = acc[rt][ct];
            #pragma unroll
            for (int r = 0; r < 4; r++) {
                int w = wbase + r;
                if (w < VV) {
                    if (SHIFT > 0 && col < SHIFT) xo[w * LL + col] = 0;
                    if (col + SHIFT < LL) xo[w * LL + col + SHIFT] = f2bf(c[r]);
                }
            }
        }
    }
}

// ---------------------------------------------------------------------------
// K3: MLP via MFMA (unchanged from R3).
// ---------------------------------------------------------------------------
__global__ __launch_bounds__(256, 3) void mlp_mfma(const float* __restrict__ x,
                                                   const u16* __restrict__ x1,
                                                   const u16* __restrict__ x2,
                                                   const u16* __restrict__ wb,
                                                   const float* __restrict__ b,
                                                   float* __restrict__ out) {
    __shared__ u16 Ht[128 * 192];   // 49152 B
    const int bid = blockIdx.x;
    const int n = bid / (SL / 128);
    const int st = bid - n * (SL / 128);
    const int s0 = st * 128;
    const int tid = threadIdx.x;

    const int lane = tid & 63;
    const int wv = tid >> 6;
    const int obase = (wv & 1) * 32;
    const int sbase = (wv >> 1) * 64;
    const int r15 = lane & 15;
    const int kg = lane >> 4;

    bf16x8 afrag[2][6];
    #pragma unroll
    for (int rt = 0; rt < 2; rt++)
        #pragma unroll
        for (int ks = 0; ks < 6; ks++)
            afrag[rt][ks] = *(const bf16x8*)(wb + (obase + rt * 16 + r15) * (3 * CC) + ks * 32 + kg * 8);

    {
        char* ldsb = (char*)Ht;
        const int spos = tid & 15;
        const int psub = tid >> 4;      // 0..15
        #pragma unroll
        for (int cg = 0; cg < 6; ++cg) {
            const int P = cg * 16 + psub;     // c-pair 0..95
            const int c = 2 * P;
            const u16* bsrc = nullptr;
            const float* fsrc = nullptr;
            if (c < CC)          fsrc = x  + ((size_t)n * CC + c) * SL + s0;
            else if (c < 2 * CC) bsrc = x1 + ((size_t)n * CC + (c - CC)) * SL + s0;
            else                 bsrc = x2 + ((size_t)n * CC + (c - 2 * CC)) * SL + s0;
            #pragma unroll
            for (int sc = 0; sc < 8; ++sc) {
                const int sl = sc * 16 + spos;   // 0..127
                u32 lo, hi;
                if (c < CC) {
                    lo = f2bf(fsrc[sl]); hi = f2bf(fsrc[sl + SL]);
                } else {
                    lo = bsrc[sl]; hi = bsrc[sl + SL];
                }
                *(u32*)(ldsb + sl * 384 + ((4 * P) ^ ((sl & 7) << 4))) = lo | (hi << 16);
            }
        }
    }
    __syncthreads();

    f32x4 acc[2][4];
    #pragma unroll
    for (int rt = 0; rt < 2; rt++)
        #pragma unroll
        for (int ct = 0; ct < 4; ct++)
            acc[rt][ct] = (f32x4){0.f, 0.f, 0.f, 0.f};

    const char* ldsb = (const char*)Ht;
    #pragma unroll
    for (int ks = 0; ks < 6; ks++) {
        bf16x8 bfr[4];
        #pragma unroll
        for (int ct = 0; ct < 4; ct++) {
            const int s = sbase + ct * 16 + r15;
            bfr[ct] = *(const bf16x8*)(ldsb + s * 384 + ((ks * 64 + kg * 16) ^ ((s & 7) << 4)));
        }
        #pragma unroll
        for (int rt = 0; rt < 2; rt++)
            #pragma unroll
            for (int ct = 0; ct < 4; ct++)
                acc[rt][ct] = __builtin_amdgcn_mfma_f32_16x16x32_bf16(afrag[rt][ks], bfr[ct], acc[rt][ct], 0, 0, 0);
    }

    #pragma unroll
    for (int rt = 0; rt < 2; rt++) {
        #pragma unroll
        for (int r = 0; r < 4; r++) {
            const int o = obase + rt * 16 + kg * 4 + r;
            const float bias = b[o];
            float* orow = out + ((size_t)n * CO + o) * SL + s0 + sbase;
            #pragma unroll
            for (int ct = 0; ct < 4; ct++)
                orow[ct * 16 + r15] = acc[rt][ct][r] + bias;
        }
    }
}

// ---------------------------------------------------------------------------
extern "C" void kernel_launch(void* const* d_in, const int* in_sizes, int n_in,
                              void* d_out, int out_size, void* d_ws, size_t ws_size,
                              hipStream_t stream) {
    const float* x     = (const float*)d_in[0];
    const float* nv1   = (const float*)d_in[1];
    const float* nv2   = (const float*)d_in[2];
    const float* et_w  = (const float*)d_in[3];
    const float* et_b  = (const float*)d_in[4];
    const float* mlp_w = (const float*)d_in[5];
    const float* mlp_b = (const float*)d_in[6];
    float* out = (float*)d_out;

    char* wsb = (char*)d_ws;
    size_t off = 0;
    auto alloc = [&](size_t bytes) {
        size_t o = off;
        off += (bytes + 255) & ~(size_t)255;
        return o;
    };
    u16*   Atb0 = (u16*)(wsb + alloc((size_t)VP * VP * 2));
    u16*   Atb1 = (u16*)(wsb + alloc((size_t)VP * VP * 2));
    float* nv1t = (float*)(wsb + alloc((size_t)VV * EE * 4));
    float* nv2t = (float*)(wsb + alloc((size_t)EE * VV * 4));
    u16*   wb   = (u16*)(wsb + alloc((size_t)CO * 3 * CC * 2));
    u16*   x1   = (u16*)(wsb + alloc((size_t)NB * CC * VV * LL * 2));
    u16*   x2   = (u16*)(wsb + alloc((size_t)NB * CC * VV * LL * 2));
    (void)in_sizes; (void)n_in; (void)out_size; (void)ws_size;

    const int embN = 2 * VV * EE + CO * 3 * CC;
    emb_kernel<<<(embN + 255) / 256, 256, 0, stream>>>(nv1, nv2, et_w, et_b, mlp_w, nv1t, nv2t, wb);
    adj_kernel<<<VP, 64, 0, stream>>>(nv1, nv2, Atb0);
    adj_kernel<<<VP, 64, 0, stream>>>(nv1t, nv2t, Atb1);
    hop_mfma<0, 0><<<NB * CC, 512, 0, stream>>>((const void*)x, Atb0, x1);
    hop_mfma<DIL, 1><<<NB * CC, 512, 0, stream>>>((const void*)x1, Atb1, x2);
    mlp_mfma<<<NB * (SL / 128), 256, 0, stream>>>(x, x1, x2, wb, mlp_b, out);
}